// Round 11
// baseline (3206.410 us; speedup 1.0000x reference)
//
#include <hip/hip_runtime.h>

// SineNet: fc1 -> LSTM(sine) -> proj.  B=64 T=1024 I=128 H=512 4H=2048 NS=32
// Round 11: R9 structure + gate-interleaved columns -> single-barrier step.
//  - 16 gangs x 16 WGs, 4 batches/gang; R9 tagged-packet protocol verbatim
//    (packet {f16 h | (t+1)<<16}, sc0 sc1, ring depth 2, memset/launch).
//  - NEW col->wave map: wave wv owns units [4wv,4wv+4); its 16 cols are
//    (unit,gate) pairs (l15 = 4*ul + gate). After 16 MFMA, the 4 gates of a
//    unit are in 4 adjacent lanes -> 3x shfl_xor gather, cell + publish done
//    by lanes (l4==0, l15%4==0): 4 batches each, 4 tagged dword stores.
//  - gat_s and barrier B1 deleted: one __syncthreads per step (B3).
//  - Pregate: same gather in shadow; pre_s[buf][unit][tt][gate][b] f32,
//    cell reads 4x b128. op_s double-buffered.

constexpr int Bb = 64;
constexpr int Tt = 1024;
constexpr int Ii = 128;
constexpr int Hh = 512;
constexpr int G4 = 2048;
constexpr int NS = 32;
constexpr int NG = 16;   // gangs
constexpr int GW = 16;   // WGs per gang
constexpr int BPG = 4;   // batches per gang

typedef _Float16 h2 __attribute__((ext_vector_type(2)));
typedef _Float16 h8 __attribute__((ext_vector_type(8)));
typedef float    f4 __attribute__((ext_vector_type(4)));
typedef unsigned int u32;
typedef u32 u32x2 __attribute__((ext_vector_type(2)));
typedef u32 u32x4 __attribute__((ext_vector_type(4)));

__device__ __forceinline__ float dot8(h8 w, h8 x, float acc) {
  h2 w0 = {w[0], w[1]}, w1 = {w[2], w[3]}, w2 = {w[4], w[5]}, w3 = {w[6], w[7]};
  h2 x0 = {x[0], x[1]}, x1 = {x[2], x[3]}, x2 = {x[4], x[5]}, x3 = {x[6], x[7]};
  acc = __builtin_amdgcn_fdot2(x0, w0, acc, false);
  acc = __builtin_amdgcn_fdot2(x1, w1, acc, false);
  acc = __builtin_amdgcn_fdot2(x2, w2, acc, false);
  acc = __builtin_amdgcn_fdot2(x3, w3, acc, false);
  return acc;
}

__device__ __forceinline__ float sigf(float x) { return 1.f / (1.f + __expf(-x)); }

// Col map: WG ss owns units [32ss,32ss+32); wave wv owns units [4wv,4wv+4).
// col16 = l15 = ul*4 + gate; global col = gate*512 + ss*32 + wv*4 + ul.

// ---- Wc = W1@W_ih (fp32) -> f16 B-frags (gate-interleaved) ----------------
__global__ void k_wc(const float* __restrict__ W1, const float* __restrict__ Wih,
                     const float* __restrict__ b1, const float* __restrict__ bl,
                     _Float16* __restrict__ Wc4, float* __restrict__ bias2) {
  const int j = blockIdx.x;   // global gate col 0..2047
  const int i = threadIdx.x;  // k index 0..127
  __shared__ float col[Hh];
  __shared__ float part[128];
  for (int k = i; k < Hh; k += 128) col[k] = Wih[k * G4 + j];
  __syncthreads();
  float s = 0.f;
  for (int k = i; k < Hh; k += 128) s += b1[k] * col[k];
  part[i] = s;
  __syncthreads();
  if (i == 0) {
    float t = bl[j];
    for (int k = 0; k < 128; k++) t += part[k];
    bias2[j] = t;
  }
  float acc = 0.f;
  const float* w1r = W1 + i * Hh;
#pragma unroll 4
  for (int k = 0; k < Hh; k++) acc += w1r[k] * col[k];
  const int gate = j >> 9, r = j & 511, ss = r >> 5, u = r & 31;
  const int wv = u >> 2, ul = u & 3;
  const int l15 = ul * 4 + gate;
  const int ks4 = i >> 5, l4 = (i >> 3) & 3, e = i & 7;
  Wc4[((ss * 8 + wv) * 4 + ks4) * 512 + (l4 * 16 + l15) * 8 + e] = (_Float16)acc;
}

// ---- W_hh (fp32 [512][2048]) -> f16 B-frags (gate-interleaved) ------------
__global__ void k_whh(const float* __restrict__ W, _Float16* __restrict__ W4) {
  const int id = blockIdx.x * 256 + threadIdx.x;  // < 131072
  const int lane = id & 63, ks = (id >> 6) & 15, wv = (id >> 10) & 7, ss = id >> 13;
  const int l15 = lane & 15, gate = l15 & 3, ul = l15 >> 2;
  const int colg = gate * 512 + ss * 32 + wv * 4 + ul;
  h8 o;
#pragma unroll
  for (int e = 0; e < 8; ++e)
    o[e] = (_Float16)W[(ks * 32 + (lane >> 4) * 8 + e) * G4 + colg];
  *(h8*)(W4 + ((ss * 8 + wv) * 16 + ks) * 512 + lane * 8) = o;
}

// ---- persistent scan: 256 WGs = 16 gangs of 16 ----------------------------
__global__ __launch_bounds__(512, 1) void k_scan(
    const float* __restrict__ x, const _Float16* __restrict__ Wc4,
    const float* __restrict__ bias2, const _Float16* __restrict__ Whh4,
    const float* __restrict__ Wo, const float* __restrict__ bo,
    float* __restrict__ out, char* __restrict__ hpub) {
  const int gid = blockIdx.x >> 4, ss = blockIdx.x & 15;
  const int tid = threadIdx.x;
  const int lane = tid & 63, wv = tid >> 6;
  const int l15 = lane & 15, l4 = lane >> 4;
  const int ul = l15 >> 2;                    // unit-local within wave
  const bool cellLane = (l4 == 0) && ((l15 & 3) == 0);
  const int unitW = wv * 4 + ul;              // WG-local unit 0..31
  const int gunit = ss * 32 + unitW;          // global unit 0..511

  __shared__ __align__(16) char hls[2][16384];  // h [16 rows][512] f16, (row<<4) XOR
  __shared__ __align__(16) char xws[4096];      // x window [8 rows][128] f16 swizzled
  __shared__ __align__(16) char wots[32768];    // Wo^T [32][512] f16 swizzled
  __shared__ __align__(16) float pre_s[2][32][36];  // [buf][unit][tt*16+gate*4+b]
  __shared__ float op_s[2][32][17];             // out-proj partials, dbuf

  // ---- register weights ----------------------------------------------------
  h8 bW[16], bC[4];
#pragma unroll
  for (int ks = 0; ks < 16; ++ks)
    bW[ks] = *(const h8*)(Whh4 + ((ss * 8 + wv) * 16 + ks) * 512 + lane * 8);
#pragma unroll
  for (int ks = 0; ks < 4; ++ks)
    bC[ks] = *(const h8*)(Wc4 + ((ss * 8 + wv) * 4 + ks) * 512 + lane * 8);

  float bIr = 0.f, bFr = 0.f, bGr = 0.f, bOr = 0.f;
  if (cellLane) {
    bIr = bias2[gunit];        bFr = bias2[512 + gunit];
    bGr = bias2[1024 + gunit]; bOr = bias2[1536 + gunit];
  }
  f4 c4 = {0.f, 0.f, 0.f, 0.f};               // cell state, 4 batches
  const float bor = (tid < NS) ? bo[tid] : 0.f;

  // ---- init LDS: zero both hls buffers + xws, stage Wo^T -------------------
#pragma unroll
  for (int q = 0; q < 2; ++q) {
    u32x4 z = {0, 0, 0, 0};
    *(u32x4*)(hls[0] + (q * 512 + tid) * 16) = z;
    *(u32x4*)(hls[1] + (q * 512 + tid) * 16) = z;
  }
  if (tid < 256) { u32x4 z = {0, 0, 0, 0}; *(u32x4*)(xws + tid * 16) = z; }
  for (int it = tid; it < Hh * NS; it += 512) {
    int k = it >> 5, n = it & 31;
    *(_Float16*)(wots + n * 1024 + ((2 * k) ^ ((n & 7) << 4))) = (_Float16)Wo[k * NS + n];
  }

  auto stage_x = [&](int t0) {  // rows tt*4+b of [8][128] f16
    if (tid < 128) {
      const int row = tid >> 4, cc = tid & 15;
      const float* src = x + ((size_t)(gid * BPG + (row & 3)) * Tt + t0 + (row >> 2)) * Ii + cc * 8;
      f4 s0 = *(const f4*)src, s1 = *(const f4*)(src + 4);
      h8 v = {(_Float16)s0[0], (_Float16)s0[1], (_Float16)s0[2], (_Float16)s0[3],
              (_Float16)s1[0], (_Float16)s1[1], (_Float16)s1[2], (_Float16)s1[3]};
      *(h8*)(xws + row * 256 + ((cc * 16) ^ ((row & 7) << 4))) = v;
    }
  };
  auto do_pregate = [&](int buf) {  // wave's 16 (unit,gate) cols; rows 0-7
    f4 pa = {0.f, 0.f, 0.f, 0.f};
#pragma unroll
    for (int ks = 0; ks < 4; ++ks) {
      const int row = l15;
      h8 a = *(const h8*)(xws + row * 256 + ((ks * 64 + l4 * 16) ^ ((row & 7) << 4)));
      pa = __builtin_amdgcn_mfma_f32_16x16x32_f16(a, bC[ks], pa, 0, 0, 0);
    }
    f4 q1, q2, q3;
#pragma unroll
    for (int e = 0; e < 4; ++e) q1[e] = __shfl_xor(pa[e], 1);
#pragma unroll
    for (int e = 0; e < 4; ++e) q2[e] = __shfl_xor(pa[e], 2);
#pragma unroll
    for (int e = 0; e < 4; ++e) q3[e] = __shfl_xor(q1[e], 2);
    if (((l15 & 3) == 0) && l4 < 2) {  // tt = l4, batches = e
      float* pw = &pre_s[buf][unitW][l4 * 16];
      *(f4*)(pw)      = pa;  // gate 0 (i)
      *(f4*)(pw + 4)  = q1;  // gate 1 (f)
      *(f4*)(pw + 8)  = q2;  // gate 2 (g)
      *(f4*)(pw + 12) = q3;  // gate 3 (o)
    }
  };
  auto op_part = [&](const char* hb, int buf) {  // WGs ss<4: h[row ss] @ Wo
    if (ss < BPG) {
      const int nn = tid & 31, pp = tid >> 5;
      float acc = 0.f;
#pragma unroll
      for (int q = 0; q < 4; ++q) {
        h8 w_ = *(const h8*)(wots + nn * 1024 + ((pp * 64 + q * 16) ^ ((nn & 7) << 4)));
        h8 hv = *(const h8*)(hb + ss * 1024 + ((pp * 64 + q * 16) ^ (ss << 4)));
        acc = dot8(w_, hv, acc);
      }
      op_s[buf][nn][pp] = acc;
    }
  };
  auto out_store = [&](int tindex, int buf) {
    if (ss < BPG && tid < NS) {
      float s_ = bor;
#pragma unroll
      for (int p = 0; p < 16; ++p) s_ += op_s[buf][tid][p];
      out[((size_t)(gid * BPG + ss) * Tt + tindex) * NS + tid] = s_;
    }
  };

  stage_x(0);
  __syncthreads();
  do_pregate(0);  // window 0 -> steps 0,1

  int cur = 0;
#pragma unroll 1
  for (int t = 0; t < Tt; ++t) {
    char* const hpg = hpub + gid * 16384 + (t & 1) * 8192;
    const char* const hc = hls[cur];
    char* const hn_ = hls[cur ^ 1];
    // ---- gate GEMM: wave's 16 (unit,gate) cols, K=512 ---------------------
    f4 g0 = {0.f, 0.f, 0.f, 0.f}, g1 = {0.f, 0.f, 0.f, 0.f};
#pragma unroll
    for (int ks = 0; ks < 16; ++ks) {
      const int row = l15;
      h8 a = *(const h8*)(hc + row * 1024 + ((ks * 64 + l4 * 16) ^ (row << 4)));
      if (ks & 1) g1 = __builtin_amdgcn_mfma_f32_16x16x32_f16(a, bW[ks], g1, 0, 0, 0);
      else        g0 = __builtin_amdgcn_mfma_f32_16x16x32_f16(a, bW[ks], g0, 0, 0, 0);
    }
    f4 gs;
#pragma unroll
    for (int e = 0; e < 4; ++e) gs[e] = g0[e] + g1[e];
    // gather 4 gates into gate-0 lanes (3 shfl chains, no barrier)
    f4 v1, v2, v3;
#pragma unroll
    for (int e = 0; e < 4; ++e) v1[e] = __shfl_xor(gs[e], 1);
#pragma unroll
    for (int e = 0; e < 4; ++e) v2[e] = __shfl_xor(gs[e], 2);
#pragma unroll
    for (int e = 0; e < 4; ++e) v3[e] = __shfl_xor(v1[e], 2);
    // ---- cell + tagged publish (in-wave, no barrier) ----------------------
    if (cellLane) {
      const int tt = t & 1, ph = (t >> 1) & 1;
      const float* pr = &pre_s[ph][unitW][tt * 16];
      f4 pI = *(const f4*)(pr);
      f4 pF = *(const f4*)(pr + 4);
      f4 pG = *(const f4*)(pr + 8);
      f4 pO = *(const f4*)(pr + 12);
      u32 pkts[4];
#pragma unroll
      for (int e = 0; e < 4; ++e) {
        float aI = gs[e] + pI[e] + bIr;
        float aF = v1[e] + pF[e] + bFr;
        float aG = v2[e] + pG[e] + bGr;
        float aO = v3[e] + pO[e] + bOr;
        float iv = sigf(aI), fv = sigf(aF), gv = __sinf(aG), ov = sigf(aO);
        c4[e] = fv * c4[e] + iv * gv;
        float hnv = ov * __sinf(c4[e]);
        _Float16 hf = (_Float16)hnv;
        pkts[e] = (u32)__builtin_bit_cast(unsigned short, hf) | ((u32)(t + 1) << 16);
      }
#pragma unroll
      for (int e = 0; e < 4; ++e) {
        u32* dst = (u32*)(hpg + ((size_t)(e * 512 + gunit)) * 4);
        asm volatile("global_store_dword %0, %1, off sc0 sc1" :: "v"(dst), "v"(pkts[e]) : "memory");
      }
    }
    // ---- shadow (no remote deps) -----------------------------------------
    if (!(t & 1)) { if (t <= 1020) stage_x(t + 2); }
    else if (t <= 1021) do_pregate(((t + 1) >> 1) & 1);
    if (t > 0) op_part(hc, t & 1);  // partials for out[t-1] from h_{t-1}
    // ---- poll own 4 packets, restage into hls[cur^1] (R9 verbatim) --------
    {
      const u32* sp = (const u32*)(hpg + (size_t)tid * 16);
      const u32 want = (u32)(t + 1);
      u32x4 v;
      while (true) {
        asm volatile("global_load_dwordx4 %0, %1, off sc0 sc1\ns_waitcnt vmcnt(0)"
                     : "=v"(v) : "v"(sp) : "memory");
        if ((v[0] >> 16) == want && (v[1] >> 16) == want &&
            (v[2] >> 16) == want && (v[3] >> 16) == want) break;
      }
      __builtin_amdgcn_sched_barrier(0);
      u32x2 d = {(v[0] & 0xFFFFu) | (v[1] << 16), (v[2] & 0xFFFFu) | (v[3] << 16)};
      const int b = tid >> 7, k = tid & 127;
      *(u32x2*)(hn_ + b * 1024 + ((k * 8) ^ (b << 4))) = d;
    }
    __syncthreads();  // B3 (the only barrier): hls[cur^1] = h_t; op_s ready
    if (t > 0) out_store(t - 1, t & 1);
    cur ^= 1;
  }
  // epilogue: out[1023] from h_1023 = hls[cur]
  op_part(hls[cur], 0);
  __syncthreads();
  out_store(1023, 0);
}

extern "C" void kernel_launch(void* const* d_in, const int* in_sizes, int n_in,
                              void* d_out, int out_size, void* d_ws, size_t ws_size,
                              hipStream_t stream) {
  const float* x   = (const float*)d_in[0];
  const float* W1  = (const float*)d_in[1];
  const float* b1  = (const float*)d_in[2];
  const float* Wih = (const float*)d_in[3];
  const float* Whh = (const float*)d_in[4];
  const float* bl  = (const float*)d_in[5];
  const float* Wo  = (const float*)d_in[6];
  const float* bo  = (const float*)d_in[7];
  float* out = (float*)d_out;

  char* ws = (char*)d_ws;
  _Float16* Wc4   = (_Float16*)(ws);            // 512 KB
  float*    bias2 = (float*)(ws + 524288);      // 8 KB
  _Float16* Whh4  = (_Float16*)(ws + 532480);   // 2 MB
  char*     hpub  = ws + 2629632;               // 256 KB (16 gangs x 2 slots x 8KB)

  (void)hipMemsetAsync(hpub, 0, 262144, stream);  // kill stale tags (replay safety)
  k_wc<<<G4, 128, 0, stream>>>(W1, Wih, b1, bl, Wc4, bias2);
  k_whh<<<512, 256, 0, stream>>>(Whh, Whh4);
  k_scan<<<256, 512, 0, stream>>>(x, Wc4, bias2, Whh4, Wo, bo, out, hpub);
}

// Round 12
// 2334.282 us; speedup vs baseline: 1.3736x; 1.3736x over previous
//
#include <hip/hip_runtime.h>

// SineNet: fc1 -> LSTM(sine) -> proj.  B=64 T=1024 I=128 H=512 4H=2048 NS=32
// Round 12: R9 structure + two-cohort software pipeline per WG.
//  - 8 gangs x 16 WGs (grid 128, 512 thr). Gang owns 8 batches: cohort A
//    (0-3) and cohort B (4-7), same t, phase-shifted inside the iteration:
//    GEMM_A | B1a | cellA+pubA, GEMM_B | B1b | cellB+pubB, shadow,
//    pollA+restageA, pollB+restageB | B3.  Publish->poll RTs hide under the
//    other cohort's compute.  3 barriers/iter.
//  - R9 tagged-packet protocol verbatim (pkt {f16 h|(t+1)<<16}, sc0 sc1,
//    ring depth 2 per cohort, hpub memset per launch).
//  - Per-WG weight layout IDENTICAL to R9 (32 units/WG, wave owns 16 cols,
//    c128 = gate*32+u): k_wc / k_whh unchanged.
//  - Pregate: one M=16 MFMA covers both cohorts' 2-step window (16 rows).

constexpr int Bb = 64;
constexpr int Tt = 1024;
constexpr int Ii = 128;
constexpr int Hh = 512;
constexpr int G4 = 2048;
constexpr int NS = 32;
constexpr int NG = 8;    // gangs
constexpr int GW = 16;   // WGs per gang
constexpr int BPG = 8;   // batches per gang (2 cohorts of 4)

typedef _Float16 h2 __attribute__((ext_vector_type(2)));
typedef _Float16 h8 __attribute__((ext_vector_type(8)));
typedef float    f4 __attribute__((ext_vector_type(4)));
typedef unsigned int u32;
typedef u32 u32x2 __attribute__((ext_vector_type(2)));
typedef u32 u32x4 __attribute__((ext_vector_type(4)));

__device__ __forceinline__ float dot8(h8 w, h8 x, float acc) {
  h2 w0 = {w[0], w[1]}, w1 = {w[2], w[3]}, w2 = {w[4], w[5]}, w3 = {w[6], w[7]};
  h2 x0 = {x[0], x[1]}, x1 = {x[2], x[3]}, x2 = {x[4], x[5]}, x3 = {x[6], x[7]};
  acc = __builtin_amdgcn_fdot2(x0, w0, acc, false);
  acc = __builtin_amdgcn_fdot2(x1, w1, acc, false);
  acc = __builtin_amdgcn_fdot2(x2, w2, acc, false);
  acc = __builtin_amdgcn_fdot2(x3, w3, acc, false);
  return acc;
}

__device__ __forceinline__ float sigf(float x) { return 1.f / (1.f + __expf(-x)); }

// WG ss owns units [32ss,32ss+32). Per-WG col c128 = gate*32+u (0..127);
// wave wv owns cols [16wv,16wv+16). Global col = gate*512 + ss*32 + u.

// ---- Wc = W1@W_ih (fp32) -> f16 B-frags (R9 verbatim) ---------------------
__global__ void k_wc(const float* __restrict__ W1, const float* __restrict__ Wih,
                     const float* __restrict__ b1, const float* __restrict__ bl,
                     _Float16* __restrict__ Wc4, float* __restrict__ bias2) {
  const int j = blockIdx.x;   // global gate col 0..2047
  const int i = threadIdx.x;  // k index 0..127
  __shared__ float col[Hh];
  __shared__ float part[128];
  for (int k = i; k < Hh; k += 128) col[k] = Wih[k * G4 + j];
  __syncthreads();
  float s = 0.f;
  for (int k = i; k < Hh; k += 128) s += b1[k] * col[k];
  part[i] = s;
  __syncthreads();
  if (i == 0) {
    float t = bl[j];
    for (int k = 0; k < 128; k++) t += part[k];
    bias2[j] = t;
  }
  float acc = 0.f;
  const float* w1r = W1 + i * Hh;
#pragma unroll 4
  for (int k = 0; k < Hh; k++) acc += w1r[k] * col[k];
  const int gate = j >> 9, r = j & 511, ss = r >> 5, u = r & 31;
  const int c128 = gate * 32 + u, cb = c128 >> 4, c = c128 & 15;
  const int lane = ((i >> 3) & 3) * 16 + c, ks4 = i >> 5, e = i & 7;
  Wc4[((ss * 8 + cb) * 4 + ks4) * 512 + lane * 8 + e] = (_Float16)acc;
}

// ---- W_hh (fp32 [512][2048]) -> f16 B-frags (R9 verbatim) -----------------
__global__ void k_whh(const float* __restrict__ W, _Float16* __restrict__ W4) {
  const int id = blockIdx.x * 256 + threadIdx.x;  // < 131072
  const int lane = id & 63, ks = (id >> 6) & 15, cb = (id >> 10) & 7, ss = id >> 13;
  const int c = lane & 15, c128 = cb * 16 + c;
  const int gate = c128 >> 5, u = c128 & 31;
  const int colg = gate * 512 + ss * 32 + u;
  h8 o;
#pragma unroll
  for (int e = 0; e < 8; ++e)
    o[e] = (_Float16)W[(ks * 32 + (lane >> 4) * 8 + e) * G4 + colg];
  *(h8*)(W4 + ((ss * 8 + cb) * 16 + ks) * 512 + lane * 8) = o;
}

// ---- persistent scan: 128 WGs = 8 gangs of 16 -----------------------------
__global__ __launch_bounds__(512, 1) void k_scan(
    const float* __restrict__ x, const _Float16* __restrict__ Wc4,
    const float* __restrict__ bias2, const _Float16* __restrict__ Whh4,
    const float* __restrict__ Wo, const float* __restrict__ bo,
    float* __restrict__ out, char* __restrict__ hpub) {
  const int gid = blockIdx.x >> 4, ss = blockIdx.x & 15;
  const int tid = threadIdx.x;
  const int lane = tid & 63, wv = tid >> 6;
  const int l15 = lane & 15, l4 = lane >> 4;

  __shared__ __align__(16) char hlsA[2][16384];  // h cohort A [16][512] f16, (row<<4) XOR
  __shared__ __align__(16) char hlsB[2][16384];  // h cohort B
  __shared__ __align__(16) char xws[4096];       // x window [16 rows][128] f16 swizzled
  __shared__ __align__(16) char wots[32768];     // Wo^T [32][512] f16 swizzled
  __shared__ __align__(16) float pre_s[2][2][8][4][33];  // [buf][tt][b8][gate][u]
  __shared__ float gatA[4][4][33];               // [b][gate][u]
  __shared__ float gatB[4][4][33];
  __shared__ float op_s[2][32][17];              // out-proj partials, dbuf

  // ---- register weights (shared by both cohorts) ---------------------------
  h8 bW[16], bC[4];
#pragma unroll
  for (int ks = 0; ks < 16; ++ks)
    bW[ks] = *(const h8*)(Whh4 + ((ss * 8 + wv) * 16 + ks) * 512 + lane * 8);
#pragma unroll
  for (int ks = 0; ks < 4; ++ks)
    bC[ks] = *(const h8*)(Wc4 + ((ss * 8 + wv) * 4 + ks) * 512 + lane * 8);

  // cell roles: tid<128 -> cohort A (b=tid>>5, u=tid&31);
  //             tid in [128,256) -> cohort B (b=(tid-128)>>5, u=tid&31)
  const int cu = tid & 31;
  float bI = 0.f, bF = 0.f, bG = 0.f, bO = 0.f;
  if (tid < 256) {
    bI = bias2[ss * 32 + cu];        bF = bias2[512 + ss * 32 + cu];
    bG = bias2[1024 + ss * 32 + cu]; bO = bias2[1536 + ss * 32 + cu];
  }
  float c_ = 0.f;  // cell state for this thread's (cohort, b, u)
  const float bor = (tid < NS) ? bo[tid] : 0.f;

  // ---- init LDS: zero hls buffers, stage Wo^T ------------------------------
#pragma unroll
  for (int q = 0; q < 2; ++q) {
    u32x4 z = {0, 0, 0, 0};
    *(u32x4*)(hlsA[0] + (q * 512 + tid) * 16) = z;
    *(u32x4*)(hlsA[1] + (q * 512 + tid) * 16) = z;
    *(u32x4*)(hlsB[0] + (q * 512 + tid) * 16) = z;
    *(u32x4*)(hlsB[1] + (q * 512 + tid) * 16) = z;
  }
  for (int it = tid; it < Hh * NS; it += 512) {
    int k = it >> 5, n = it & 31;
    *(_Float16*)(wots + n * 1024 + ((2 * k) ^ ((n & 7) << 4))) = (_Float16)Wo[k * NS + n];
  }

  auto stage_x = [&](int t0) {  // rows tt*8+b (b 0..7) of [16][128] f16
    if (tid < 256) {
      const int row = tid >> 4, cc = tid & 15;
      const float* src = x + ((size_t)(gid * BPG + (row & 7)) * Tt + t0 + (row >> 3)) * Ii + cc * 8;
      f4 s0 = *(const f4*)src, s1 = *(const f4*)(src + 4);
      h8 v = {(_Float16)s0[0], (_Float16)s0[1], (_Float16)s0[2], (_Float16)s0[3],
              (_Float16)s1[0], (_Float16)s1[1], (_Float16)s1[2], (_Float16)s1[3]};
      *(h8*)(xws + row * 256 + ((cc * 16) ^ ((row & 7) << 4))) = v;
    }
  };
  auto do_pregate = [&](int buf) {  // one M=16 MFMA pass, both cohorts
    f4 pa = {0.f, 0.f, 0.f, 0.f};
#pragma unroll
    for (int ks = 0; ks < 4; ++ks) {
      const int row = l15;
      h8 a = *(const h8*)(xws + row * 256 + ((ks * 64 + l4 * 16) ^ ((row & 7) << 4)));
      pa = __builtin_amdgcn_mfma_f32_16x16x32_f16(a, bC[ks], pa, 0, 0, 0);
    }
    const int c128 = wv * 16 + l15, gam = c128 >> 5, u = c128 & 31;
#pragma unroll
    for (int e = 0; e < 4; ++e) {
      const int row = l4 * 4 + e;  // 0..15 = tt*8 + b
      pre_s[buf][row >> 3][row & 7][gam][u] = pa[e];
    }
  };
  auto op_part = [&](const char* hAc, const char* hBc, int buf) {  // ss<8
    if (ss < BPG) {
      const char* hb = (ss < 4 ? hAc : hBc) + (ss & 3) * 1024;
      const int r = ss & 3;
      const int nn = tid & 31, pp = tid >> 5;
      float acc = 0.f;
#pragma unroll
      for (int q = 0; q < 4; ++q) {
        h8 w_ = *(const h8*)(wots + nn * 1024 + ((pp * 64 + q * 16) ^ ((nn & 7) << 4)));
        h8 hv = *(const h8*)(hb + ((pp * 64 + q * 16) ^ (r << 4)));
        acc = dot8(w_, hv, acc);
      }
      op_s[buf][nn][pp] = acc;
    }
  };
  auto out_store = [&](int tindex, int buf) {
    if (ss < BPG && tid < NS) {
      float s_ = bor;
#pragma unroll
      for (int p = 0; p < 16; ++p) s_ += op_s[buf][tid][p];
      out[((size_t)(gid * BPG + ss) * Tt + tindex) * NS + tid] = s_;
    }
  };
  auto gemm = [&](const char* hc, float (*gat)[4][33]) {
    f4 g0 = {0.f, 0.f, 0.f, 0.f}, g1 = {0.f, 0.f, 0.f, 0.f};
#pragma unroll
    for (int ks = 0; ks < 16; ++ks) {
      const int row = l15;
      h8 a = *(const h8*)(hc + row * 1024 + ((ks * 64 + l4 * 16) ^ (row << 4)));
      if (ks & 1) g1 = __builtin_amdgcn_mfma_f32_16x16x32_f16(a, bW[ks], g1, 0, 0, 0);
      else        g0 = __builtin_amdgcn_mfma_f32_16x16x32_f16(a, bW[ks], g0, 0, 0, 0);
    }
    if (l4 == 0) {
      const int c128 = wv * 16 + l15, gam = c128 >> 5, u = c128 & 31;
#pragma unroll
      for (int e = 0; e < 4; ++e) gat[e][gam][u] = g0[e] + g1[e];
    }
  };
  auto cell_pub = [&](float (*gat)[4][33], int bloc, int t, char* slot) {
    // bloc = batch within cohort; pre_s b-index = cohortBase + bloc
    const int tt = t & 1, ph = (t >> 1) & 1;
    const int bp = (tid < 128 ? 0 : 4) + bloc;
    float aI = gat[bloc][0][cu] + pre_s[ph][tt][bp][0][cu] + bI;
    float aF = gat[bloc][1][cu] + pre_s[ph][tt][bp][1][cu] + bF;
    float aG = gat[bloc][2][cu] + pre_s[ph][tt][bp][2][cu] + bG;
    float aO = gat[bloc][3][cu] + pre_s[ph][tt][bp][3][cu] + bO;
    float iv = sigf(aI), fv = sigf(aF), gv = __sinf(aG), ov = sigf(aO);
    c_ = fv * c_ + iv * gv;
    float hnv = ov * __sinf(c_);
    _Float16 hf = (_Float16)hnv;
    u32 pkt = (u32)__builtin_bit_cast(unsigned short, hf) | ((u32)(t + 1) << 16);
    u32* dst = (u32*)(slot + ((size_t)(bloc * 512 + ss * 32 + cu)) * 4);
    asm volatile("global_store_dword %0, %1, off sc0 sc1" :: "v"(dst), "v"(pkt) : "memory");
  };
  auto poll_restage = [&](const char* slot, char* hn_, u32 want) {
    const u32* sp = (const u32*)(slot + (size_t)tid * 16);
    u32x4 v;
    while (true) {
      asm volatile("global_load_dwordx4 %0, %1, off sc0 sc1\ns_waitcnt vmcnt(0)"
                   : "=v"(v) : "v"(sp) : "memory");
      if ((v[0] >> 16) == want && (v[1] >> 16) == want &&
          (v[2] >> 16) == want && (v[3] >> 16) == want) break;
    }
    __builtin_amdgcn_sched_barrier(0);
    u32x2 d = {(v[0] & 0xFFFFu) | (v[1] << 16), (v[2] & 0xFFFFu) | (v[3] << 16)};
    const int b = tid >> 7, k = tid & 127;
    *(u32x2*)(hn_ + b * 1024 + ((k * 8) ^ (b << 4))) = d;
  };

  stage_x(0);
  __syncthreads();
  do_pregate(0);  // window 0 -> steps 0,1 (both cohorts)

  int cur = 0;
#pragma unroll 1
  for (int t = 0; t < Tt; ++t) {
    char* const slotA = hpub + ((gid * 2 + 0) * 2 + (t & 1)) * 8192;
    char* const slotB = hpub + ((gid * 2 + 1) * 2 + (t & 1)) * 8192;
    // ---- cohort A: GEMM -> B1a -> cell+publish ----------------------------
    gemm(hlsA[cur], gatA);
    __syncthreads();  // B1a
    if (tid < 128) cell_pub(gatA, tid >> 5, t, slotA);
    // ---- cohort B: GEMM (waves 2-7 start immediately) -> B1b -> cell+pub --
    gemm(hlsB[cur], gatB);
    __syncthreads();  // B1b
    if (tid >= 128 && tid < 256) cell_pub(gatB, (tid - 128) >> 5, t, slotB);
    // ---- shadow -----------------------------------------------------------
    if (!(t & 1)) { if (t <= 1020) stage_x(t + 2); }
    else if (t <= 1021) do_pregate(((t + 1) >> 1) & 1);
    if (t > 0) op_part(hlsA[cur], hlsB[cur], t & 1);  // for out[t-1]
    // ---- polls (A's RT hid under GEMM_B+cellB; B's under shadow+pollA) ----
    poll_restage(slotA, hlsA[cur ^ 1], (u32)(t + 1));
    poll_restage(slotB, hlsB[cur ^ 1], (u32)(t + 1));
    __syncthreads();  // B3
    if (t > 0) out_store(t - 1, t & 1);
    cur ^= 1;
  }
  // epilogue: out[1023]
  op_part(hlsA[cur], hlsB[cur], 0);
  __syncthreads();
  out_store(1023, 0);
}

extern "C" void kernel_launch(void* const* d_in, const int* in_sizes, int n_in,
                              void* d_out, int out_size, void* d_ws, size_t ws_size,
                              hipStream_t stream) {
  const float* x   = (const float*)d_in[0];
  const float* W1  = (const float*)d_in[1];
  const float* b1  = (const float*)d_in[2];
  const float* Wih = (const float*)d_in[3];
  const float* Whh = (const float*)d_in[4];
  const float* bl  = (const float*)d_in[5];
  const float* Wo  = (const float*)d_in[6];
  const float* bo  = (const float*)d_in[7];
  float* out = (float*)d_out;

  char* ws = (char*)d_ws;
  _Float16* Wc4   = (_Float16*)(ws);            // 512 KB
  float*    bias2 = (float*)(ws + 524288);      // 8 KB
  _Float16* Whh4  = (_Float16*)(ws + 532480);   // 2 MB
  char*     hpub  = ws + 2629632;               // 256 KB (8 gangs x 2 cohorts x 2 slots x 8KB)

  (void)hipMemsetAsync(hpub, 0, 262144, stream);  // kill stale tags (replay safety)
  k_wc<<<G4, 128, 0, stream>>>(W1, Wih, b1, bl, Wc4, bias2);
  k_whh<<<512, 256, 0, stream>>>(Whh, Whh4);
  k_scan<<<NG * GW, 512, 0, stream>>>(x, Wc4, bias2, Whh4, Wo, bo, out, hpub);
}

// Round 13
// 1981.143 us; speedup vs baseline: 1.6185x; 1.1783x over previous
//
#include <hip/hip_runtime.h>

// SineNet: fc1 -> LSTM(sine) -> proj.  B=64 T=1024 I=128 H=512 4H=2048 NS=32
// Round 13: R9 verbatim + early-issued poll (RT hidden under shadow work).
//  - 16 gangs x 16 WGs, 4 batches/gang; tagged-packet protocol (pkt =
//    {f16 h | (t+1)<<16}, sc0 sc1, ring depth 2, hpub memset per launch).
//  - Change vs R9: the first poll global_load_dwordx4 is ISSUED right after
//    the publish store (issue-only asm, result held in regs); shadow work
//    (x-stage / pregate MFMA / out-proj partials) executes while the load is
//    in flight; then vmcnt(0) + tag check; back-to-back retries on miss.
//  - 2 barriers/step (B1 gat_s, B3 restage); hls (row<<4) XOR swizzle.

constexpr int Bb = 64;
constexpr int Tt = 1024;
constexpr int Ii = 128;
constexpr int Hh = 512;
constexpr int G4 = 2048;
constexpr int NS = 32;
constexpr int NG = 16;   // gangs
constexpr int GW = 16;   // WGs per gang
constexpr int BPG = 4;   // batches per gang

typedef _Float16 h2 __attribute__((ext_vector_type(2)));
typedef _Float16 h8 __attribute__((ext_vector_type(8)));
typedef float    f4 __attribute__((ext_vector_type(4)));
typedef unsigned int u32;
typedef u32 u32x2 __attribute__((ext_vector_type(2)));
typedef u32 u32x4 __attribute__((ext_vector_type(4)));

__device__ __forceinline__ float dot8(h8 w, h8 x, float acc) {
  h2 w0 = {w[0], w[1]}, w1 = {w[2], w[3]}, w2 = {w[4], w[5]}, w3 = {w[6], w[7]};
  h2 x0 = {x[0], x[1]}, x1 = {x[2], x[3]}, x2 = {x[4], x[5]}, x3 = {x[6], x[7]};
  acc = __builtin_amdgcn_fdot2(x0, w0, acc, false);
  acc = __builtin_amdgcn_fdot2(x1, w1, acc, false);
  acc = __builtin_amdgcn_fdot2(x2, w2, acc, false);
  acc = __builtin_amdgcn_fdot2(x3, w3, acc, false);
  return acc;
}

__device__ __forceinline__ float sigf(float x) { return 1.f / (1.f + __expf(-x)); }

// WG ss owns units [32ss,32ss+32). Per-WG col c128 = gate*32+u (0..127);
// col-block cb = c128>>4 (one per wave); global col = gate*512 + ss*32 + u.

// ---- Wc = W1@W_ih (fp32) -> f16 B-frags; bias2 = b1@W_ih + b_lstm ---------
__global__ void k_wc(const float* __restrict__ W1, const float* __restrict__ Wih,
                     const float* __restrict__ b1, const float* __restrict__ bl,
                     _Float16* __restrict__ Wc4, float* __restrict__ bias2) {
  const int j = blockIdx.x;   // global gate col 0..2047
  const int i = threadIdx.x;  // k index 0..127
  __shared__ float col[Hh];
  __shared__ float part[128];
  for (int k = i; k < Hh; k += 128) col[k] = Wih[k * G4 + j];
  __syncthreads();
  float s = 0.f;
  for (int k = i; k < Hh; k += 128) s += b1[k] * col[k];
  part[i] = s;
  __syncthreads();
  if (i == 0) {
    float t = bl[j];
    for (int k = 0; k < 128; k++) t += part[k];
    bias2[j] = t;
  }
  float acc = 0.f;
  const float* w1r = W1 + i * Hh;
#pragma unroll 4
  for (int k = 0; k < Hh; k++) acc += w1r[k] * col[k];
  const int gate = j >> 9, r = j & 511, ss = r >> 5, u = r & 31;
  const int c128 = gate * 32 + u, cb = c128 >> 4, c = c128 & 15;
  const int lane = ((i >> 3) & 3) * 16 + c, ks4 = i >> 5, e = i & 7;
  Wc4[((ss * 8 + cb) * 4 + ks4) * 512 + lane * 8 + e] = (_Float16)acc;
}

// ---- W_hh (fp32 [512][2048]) -> f16 B-frags -------------------------------
__global__ void k_whh(const float* __restrict__ W, _Float16* __restrict__ W4) {
  const int id = blockIdx.x * 256 + threadIdx.x;  // < 131072
  const int lane = id & 63, ks = (id >> 6) & 15, cb = (id >> 10) & 7, ss = id >> 13;
  const int c = lane & 15, c128 = cb * 16 + c;
  const int gate = c128 >> 5, u = c128 & 31;
  const int colg = gate * 512 + ss * 32 + u;
  h8 o;
#pragma unroll
  for (int e = 0; e < 8; ++e)
    o[e] = (_Float16)W[(ks * 32 + (lane >> 4) * 8 + e) * G4 + colg];
  *(h8*)(W4 + ((ss * 8 + cb) * 16 + ks) * 512 + lane * 8) = o;
}

// ---- persistent scan: 256 WGs = 16 gangs of 16 ----------------------------
__global__ __launch_bounds__(512, 1) void k_scan(
    const float* __restrict__ x, const _Float16* __restrict__ Wc4,
    const float* __restrict__ bias2, const _Float16* __restrict__ Whh4,
    const float* __restrict__ Wo, const float* __restrict__ bo,
    float* __restrict__ out, char* __restrict__ hpub) {
  const int gid = blockIdx.x >> 4, ss = blockIdx.x & 15;
  const int tid = threadIdx.x;
  const int lane = tid & 63, wv = tid >> 6;
  const int l15 = lane & 15, l4 = lane >> 4;

  __shared__ __align__(16) char hls[2][16384];  // h [16 rows][512] f16, (row<<4) XOR swizzle
  __shared__ __align__(16) char xws[4096];      // x window [8 rows][128] f16 swizzled (rows 8-15 zero)
  __shared__ __align__(16) char wots[32768];    // Wo^T [32][512] f16 swizzled
  __shared__ __align__(16) float pre_s[2][2][4][4][33];  // [buf][tt][b][gate][u]
  __shared__ float gat_s[4][4][33];             // [b][gate][u]
  __shared__ float op_s[32][17];

  // ---- register weights: wave wv owns col-block cb = wv --------------------
  h8 bW[16], bC[4];
#pragma unroll
  for (int ks = 0; ks < 16; ++ks)
    bW[ks] = *(const h8*)(Whh4 + ((ss * 8 + wv) * 16 + ks) * 512 + lane * 8);
#pragma unroll
  for (int ks = 0; ks < 4; ++ks)
    bC[ks] = *(const h8*)(Wc4 + ((ss * 8 + wv) * 4 + ks) * 512 + lane * 8);

  const int b8 = tid >> 5, ml = tid & 31;  // cell role (tid<128): batch, unit
  const float bI = bias2[ss * 32 + ml],        bF = bias2[512 + ss * 32 + ml],
              bG = bias2[1024 + ss * 32 + ml], bO = bias2[1536 + ss * 32 + ml];
  const int nn = tid & 31, pp = tid >> 5;  // out-proj role
  const float bor = (tid < NS) ? bo[tid] : 0.f;

  // ---- init LDS: zero both hls buffers + xws, stage Wo^T -------------------
#pragma unroll
  for (int q = 0; q < 2; ++q) {
    u32x4 z = {0, 0, 0, 0};
    *(u32x4*)(hls[0] + (q * 512 + tid) * 16) = z;
    *(u32x4*)(hls[1] + (q * 512 + tid) * 16) = z;
  }
  if (tid < 256) { u32x4 z = {0, 0, 0, 0}; *(u32x4*)(xws + tid * 16) = z; }
  for (int it = tid; it < Hh * NS; it += 512) {
    int k = it >> 5, n = it & 31;
    *(_Float16*)(wots + n * 1024 + ((2 * k) ^ ((n & 7) << 4))) = (_Float16)Wo[k * NS + n];
  }
  float c_ = 0.f;

  auto stage_x = [&](int t0) {  // rows tt*4+b of [8][128] f16
    if (tid < 128) {
      const int row = tid >> 4, cc = tid & 15;
      const float* src = x + ((size_t)(gid * BPG + (row & 3)) * Tt + t0 + (row >> 2)) * Ii + cc * 8;
      f4 s0 = *(const f4*)src, s1 = *(const f4*)(src + 4);
      h8 v = {(_Float16)s0[0], (_Float16)s0[1], (_Float16)s0[2], (_Float16)s0[3],
              (_Float16)s1[0], (_Float16)s1[1], (_Float16)s1[2], (_Float16)s1[3]};
      *(h8*)(xws + row * 256 + ((cc * 16) ^ ((row & 7) << 4))) = v;
    }
  };
  auto do_pregate = [&](int buf) {  // wave wv: its 16 cols; C rows 0-7 used
    f4 pa = {0.f, 0.f, 0.f, 0.f};
#pragma unroll
    for (int ks = 0; ks < 4; ++ks) {
      const int row = l15;
      h8 a = *(const h8*)(xws + row * 256 + ((ks * 64 + l4 * 16) ^ ((row & 7) << 4)));
      pa = __builtin_amdgcn_mfma_f32_16x16x32_f16(a, bC[ks], pa, 0, 0, 0);
    }
    if (l4 < 2) {
      const int c128 = wv * 16 + l15, gam = c128 >> 5, u = c128 & 31;
#pragma unroll
      for (int e = 0; e < 4; ++e) {
        const int row = l4 * 4 + e;  // 0..7 = tt*4 + b
        pre_s[buf][row >> 2][row & 3][gam][u] = pa[e];
      }
    }
  };
  auto op_part = [&](const char* hb) {  // WGs ss<4: partials of h[row ss] @ Wo
    if (ss < BPG) {
      float acc = 0.f;
#pragma unroll
      for (int q = 0; q < 4; ++q) {
        h8 w_ = *(const h8*)(wots + nn * 1024 + ((pp * 64 + q * 16) ^ ((nn & 7) << 4)));
        h8 hv = *(const h8*)(hb + ss * 1024 + ((pp * 64 + q * 16) ^ (ss << 4)));
        acc = dot8(w_, hv, acc);
      }
      op_s[nn][pp] = acc;
    }
  };

  stage_x(0);
  __syncthreads();
  do_pregate(0);  // steps 0,1

  int cur = 0;
#pragma unroll 1
  for (int t = 0; t < Tt; ++t) {
    char* const hpg = hpub + gid * 16384 + (t & 1) * 8192;
    const char* const hc = hls[cur];
    char* const hn_ = hls[cur ^ 1];
    // ---- gate GEMM: wave's 16 cols, K=512 ---------------------------------
    {
      f4 g0 = {0.f, 0.f, 0.f, 0.f}, g1 = {0.f, 0.f, 0.f, 0.f};
#pragma unroll
      for (int ks = 0; ks < 16; ++ks) {
        const int row = l15;
        h8 a = *(const h8*)(hc + row * 1024 + ((ks * 64 + l4 * 16) ^ (row << 4)));
        if (ks & 1) g1 = __builtin_amdgcn_mfma_f32_16x16x32_f16(a, bW[ks], g1, 0, 0, 0);
        else        g0 = __builtin_amdgcn_mfma_f32_16x16x32_f16(a, bW[ks], g0, 0, 0, 0);
      }
      if (l4 == 0) {
        const int c128 = wv * 16 + l15, gam = c128 >> 5, u = c128 & 31;
#pragma unroll
        for (int e = 0; e < 4; ++e) gat_s[e][gam][u] = g0[e] + g1[e];
      }
    }
    __syncthreads();  // B1: gat_s ready
    // ---- cell update + tagged-packet publish ------------------------------
    if (tid < 128) {
      const int ph = (t >> 1) & 1, tt = t & 1;
      float aI = gat_s[b8][0][ml] + pre_s[ph][tt][b8][0][ml] + bI;
      float aF = gat_s[b8][1][ml] + pre_s[ph][tt][b8][1][ml] + bF;
      float aG = gat_s[b8][2][ml] + pre_s[ph][tt][b8][2][ml] + bG;
      float aO = gat_s[b8][3][ml] + pre_s[ph][tt][b8][3][ml] + bO;
      float iv = sigf(aI), fv = sigf(aF), gv = __sinf(aG), ov = sigf(aO);
      c_ = fv * c_ + iv * gv;
      float hnv = ov * __sinf(c_);
      _Float16 hf = (_Float16)hnv;
      u32 pkt = (u32)__builtin_bit_cast(unsigned short, hf) | ((u32)(t + 1) << 16);
      u32* dst = (u32*)(hpg + ((size_t)(b8 * 512 + ss * 32 + ml)) * 4);
      asm volatile("global_store_dword %0, %1, off sc0 sc1" :: "v"(dst), "v"(pkt) : "memory");
    }
    // ---- EARLY poll issue (result lands while shadow runs) ----------------
    const u32* sp = (const u32*)(hpg + (size_t)tid * 16);
    const u32 want = (u32)(t + 1);
    u32x4 v;
    asm volatile("global_load_dwordx4 %0, %1, off sc0 sc1"
                 : "=&v"(v) : "v"(sp) : "memory");
    // ---- shadow (no remote deps) -----------------------------------------
    if (!(t & 1)) { if (t <= 1020) stage_x(t + 2); }
    else if (t <= 1021) do_pregate(((t + 1) >> 1) & 1);
    if (t > 0) op_part(hc);  // partials for out[t-1] from h_{t-1}
    // ---- complete first attempt; retry on miss ----------------------------
    asm volatile("s_waitcnt vmcnt(0)" ::: "memory");
    __builtin_amdgcn_sched_barrier(0);
    while (!((v[0] >> 16) == want && (v[1] >> 16) == want &&
             (v[2] >> 16) == want && (v[3] >> 16) == want)) {
      asm volatile("global_load_dwordx4 %0, %1, off sc0 sc1\ns_waitcnt vmcnt(0)"
                   : "=v"(v) : "v"(sp) : "memory");
    }
    __builtin_amdgcn_sched_barrier(0);
    {
      u32x2 d = {(v[0] & 0xFFFFu) | (v[1] << 16), (v[2] & 0xFFFFu) | (v[3] << 16)};
      const int b = tid >> 7, k = tid & 127;
      *(u32x2*)(hn_ + b * 1024 + ((k * 8) ^ (b << 4))) = d;
    }
    __syncthreads();  // B3: hls[cur^1] = h_t; op_s ready
    if (t > 0 && ss < BPG && tid < NS) {
      float s_ = bor;
#pragma unroll
      for (int p = 0; p < 16; ++p) s_ += op_s[tid][p];
      out[((size_t)(gid * BPG + ss) * Tt + (t - 1)) * NS + tid] = s_;
    }
    cur ^= 1;
  }
  // epilogue: out[1023] from h_1023 = hls[cur]
  op_part(hls[cur]);
  __syncthreads();
  if (ss < BPG && tid < NS) {
    float s_ = bor;
#pragma unroll
    for (int p = 0; p < 16; ++p) s_ += op_s[tid][p];
    out[((size_t)(gid * BPG + ss) * Tt + 1023) * NS + tid] = s_;
  }
}

extern "C" void kernel_launch(void* const* d_in, const int* in_sizes, int n_in,
                              void* d_out, int out_size, void* d_ws, size_t ws_size,
                              hipStream_t stream) {
  const float* x   = (const float*)d_in[0];
  const float* W1  = (const float*)d_in[1];
  const float* b1  = (const float*)d_in[2];
  const float* Wih = (const float*)d_in[3];
  const float* Whh = (const float*)d_in[4];
  const float* bl  = (const float*)d_in[5];
  const float* Wo  = (const float*)d_in[6];
  const float* bo  = (const float*)d_in[7];
  float* out = (float*)d_out;

  char* ws = (char*)d_ws;
  _Float16* Wc4   = (_Float16*)(ws);            // 512 KB
  float*    bias2 = (float*)(ws + 524288);      // 8 KB
  _Float16* Whh4  = (_Float16*)(ws + 532480);   // 2 MB
  char*     hpub  = ws + 2629632;               // 256 KB (16 gangs x 2 slots x 8KB)

  (void)hipMemsetAsync(hpub, 0, 262144, stream);  // kill stale tags (replay safety)
  k_wc<<<G4, 128, 0, stream>>>(W1, Wih, b1, bl, Wc4, bias2);
  k_whh<<<512, 256, 0, stream>>>(Whh, Whh4);
  k_scan<<<256, 512, 0, stream>>>(x, Wc4, bias2, Whh4, Wo, bo, out, hpub);
}